// Round 9
// baseline (76.465 us; speedup 1.0000x reference)
//
#include <hip/hip_runtime.h>
#include <hip/hip_bf16.h>
#include <math.h>

#define B_ 4
#define S_ 2048
#define D_ 256
#define H_ 8

typedef __attribute__((ext_vector_type(8))) __bf16 bf16x8;
typedef __attribute__((ext_vector_type(4))) float f32x4;

__device__ inline ushort f2bf(float x) {
  unsigned u = __builtin_bit_cast(unsigned, x);
  unsigned r = u + 0x7fffu + ((u >> 16) & 1u);
  return (ushort)(r >> 16);
}

__device__ inline unsigned cvtpk(float lo, float hi) {
  unsigned r;
  asm("v_cvt_pk_bf16_f32 %0, %1, %2" : "=v"(r) : "v"(lo), "v"(hi));
  return r;
}

__device__ inline bf16x8 load8(const ushort* p) {
  return __builtin_bit_cast(bf16x8, *(const uint4*)p);
}

// ---- prepass: f32 -> bf16 (pos) ----
__global__ void cvt_bf16_kernel(const float* __restrict__ in, ushort* __restrict__ out, int n4) {
  int i = blockIdx.x * blockDim.x + threadIdx.x;
  if (i >= n4) return;
  float4 v = ((const float4*)in)[i];
  ushort4 o;
  o.x = f2bf(v.x); o.y = f2bf(v.y); o.z = f2bf(v.z); o.w = f2bf(v.w);
  ((ushort4*)out)[i] = o;
}

// ---- prepass: Vt[bh][d][s], mask folded in, key-permuted columns per 32-tile ----
__global__ void build_vt_kernel(const float* __restrict__ x, const float* __restrict__ mask,
                                ushort* __restrict__ vt) {
  __shared__ ushort tile[32][33];
  int s0 = blockIdx.x * 32;
  int bh = blockIdx.y;
  int b = bh >> 3, h = bh & 7;
  int tx = threadIdx.x, ty = threadIdx.y;
  float mval = mask[b * S_ + s0 + ty];
  tile[ty][tx] = f2bf(x[((size_t)(b * S_ + s0 + ty)) * D_ + h * 32 + tx] * mval);
  __syncthreads();
  int kx = ((tx >> 1) & 12) + (tx & 3) + ((tx & 4) << 2);  // kappa(tx)
  vt[((size_t)bh * 32 + ty) * S_ + s0 + tx] = tile[kx][ty];
}

// ---- prepass: kappa-permuted bf16 mask ----
__global__ void build_maskp_kernel(const float* __restrict__ mask, ushort* __restrict__ maskp, int n) {
  int i = blockIdx.x * blockDim.x + threadIdx.x;
  if (i >= n) return;
  int t = i & 31;
  int kx = ((t >> 1) & 12) + (t & 3) + ((t & 4) << 2);
  maskp[i] = f2bf(mask[(i & ~31) + kx]);
}

// ---- prepass: Wt[n][k] = W[k][n] as bf16 ----
__global__ void build_wt_kernel(const float* __restrict__ w, ushort* __restrict__ wt) {
  __shared__ ushort tile[32][33];
  int k0 = blockIdx.x * 32;
  int n0 = blockIdx.y * 32;
  int tx = threadIdx.x, ty = threadIdx.y;
  tile[ty][tx] = f2bf(w[(k0 + ty) * D_ + n0 + tx]);
  __syncthreads();
  wt[(n0 + ty) * D_ + k0 + tx] = tile[tx][ty];
}

// ---- flash attention: 64 q/wave, in-block split-K x4, cross-block split-K x2 (grid.y),
//      4-buffer LDS reduction (R5-green), f32 po/pl epilogue (R4-green) ----
__global__ __launch_bounds__(256, 3) void attn_kernel(
    const ushort* __restrict__ posbf,
    const ushort* __restrict__ vt,
    const ushort* __restrict__ maskp,
    float* __restrict__ po,   // [2][B][S][D] f32 partial outputs
    float* __restrict__ pl) { // [2][32][S]   f32 partial lsums
  __shared__ float lo[4][64][32];  // [wave][q][d] f32 partial outputs
  __shared__ float ll[4][64];      // [wave][q] partial lsums

  const int tid = threadIdx.x;
  const int wid = tid >> 6, lane = tid & 63;
  const int c = lane & 15, g = lane >> 4;
  const int blk = blockIdx.x;
  const int kc = blockIdx.y;  // 0/1: key half
  const int bh = blk & 31;    // XCD co-location: all blocks of one bh -> same XCD
  const int qc = blk >> 5;    // 0..31
  const int b = bh >> 3, h = bh & 7;
  const int q0 = qc * 64;
  const int koff = kc * 1024 + wid * 256;  // this wave's 256-key slice

  const ushort* posb = posbf + (size_t)b * S_ * D_;
  const ushort* vtb = vt + (size_t)bh * 32 * S_;

  // 4 Q fragments (B' operand): col j covers queries q0+16j+c
  bf16x8 fq[4];
#pragma unroll
  for (int j = 0; j < 4; ++j)
    fq[j] = load8(posb + (size_t)(q0 + 16 * j + c) * D_ + h * 32 + g * 8);

  const ushort* kb = posb + (size_t)(koff + c) * D_ + h * 32 + g * 8;
  const ushort* vb = vtb + (size_t)c * S_ + koff + g * 8;
  const ushort* mb = maskp + (size_t)b * S_ + koff + g * 8;

  const f32x4 zero = {0.f, 0.f, 0.f, 0.f};
  f32x4 o0[4], o1[4], o2[4];
#pragma unroll
  for (int j = 0; j < 4; ++j) { o0[j] = zero; o1[j] = zero; o2[j] = zero; }

  const float C1 = 0.42044820762685725f * 1.44269504088896340f; // RS * log2e
  const float C2 = -16.0f * 1.44269504088896340f;               // -OFF * log2e

  bf16x8 ak0 = load8(kb);
  bf16x8 ak1 = load8(kb + 16 * D_);
  bf16x8 av0 = load8(vb);
  bf16x8 av1 = load8(vb + 16 * S_);
  bf16x8 am  = load8(mb);

  for (int t = 0; t < 8; ++t) {
    int tn = (t + 1) & 7;  // wraps; final reload unused
    const ushort* kbn = kb + (size_t)tn * 32 * D_;
    bf16x8 nk0 = load8(kbn);
    bf16x8 nk1 = load8(kbn + 16 * D_);
    bf16x8 nv0 = load8(vb + tn * 32);
    bf16x8 nv1 = load8(vb + 16 * S_ + tn * 32);
    bf16x8 nm  = load8(mb + tn * 32);

#pragma unroll
    for (int j = 0; j < 4; ++j) {
      f32x4 s0 = __builtin_amdgcn_mfma_f32_16x16x32_bf16(ak0, fq[j], zero, 0, 0, 0);
      f32x4 s1 = __builtin_amdgcn_mfma_f32_16x16x32_bf16(ak1, fq[j], zero, 0, 0, 0);

      float p0 = __builtin_amdgcn_exp2f(fmaf(s0[0], C1, C2));
      float p1 = __builtin_amdgcn_exp2f(fmaf(s0[1], C1, C2));
      float p2 = __builtin_amdgcn_exp2f(fmaf(s0[2], C1, C2));
      float p3 = __builtin_amdgcn_exp2f(fmaf(s0[3], C1, C2));
      float p4 = __builtin_amdgcn_exp2f(fmaf(s1[0], C1, C2));
      float p5 = __builtin_amdgcn_exp2f(fmaf(s1[1], C1, C2));
      float p6 = __builtin_amdgcn_exp2f(fmaf(s1[2], C1, C2));
      float p7 = __builtin_amdgcn_exp2f(fmaf(s1[3], C1, C2));

      uint4 uw = make_uint4(cvtpk(p0, p1), cvtpk(p2, p3), cvtpk(p4, p5), cvtpk(p6, p7));
      bf16x8 fp = __builtin_bit_cast(bf16x8, uw);

      o0[j] = __builtin_amdgcn_mfma_f32_16x16x32_bf16(fp, av0, o0[j], 0, 0, 0);
      o1[j] = __builtin_amdgcn_mfma_f32_16x16x32_bf16(fp, av1, o1[j], 0, 0, 0);
      o2[j] = __builtin_amdgcn_mfma_f32_16x16x32_bf16(fp, am, o2[j], 0, 0, 0);
    }

    ak0 = nk0; ak1 = nk1; av0 = nv0; av1 = nv1; am = nm;
  }

  // deposit wave partials to LDS (R5-green verbatim)
#pragma unroll
  for (int j = 0; j < 4; ++j) {
#pragma unroll
    for (int r = 0; r < 4; ++r) {
      int ql = 16 * j + 4 * g + r;
      lo[wid][ql][c] = o0[j][r];
      lo[wid][ql][16 + c] = o1[j][r];
      if (c == 0) ll[wid][ql] = o2[j][r];
    }
  }
  __syncthreads();

  // write f32 partials for this kc slice
  float* pob = po + (size_t)kc * B_ * S_ * D_ + (size_t)(b * S_ + q0) * D_ + h * 32;
  for (int e = tid; e < 64 * 32; e += 256) {
    int q = e >> 5, d = e & 31;
    pob[(size_t)q * D_ + d] = lo[0][q][d] + lo[1][q][d] + lo[2][q][d] + lo[3][q][d];
  }
  if (tid < 64)
    pl[((size_t)kc * 32 + bh) * S_ + q0 + tid] =
        ll[0][tid] + ll[1][tid] + ll[2][tid] + ll[3][tid];
}

// ---- combine halves: attnbf = bf16((poA+poB) / (plA+plB))  (R4-green verbatim) ----
__global__ __launch_bounds__(256) void combine_kernel(
    const float* __restrict__ po, const float* __restrict__ pl,
    ushort* __restrict__ attnbf) {
  int i = blockIdx.x * blockDim.x + threadIdx.x;  // float4 index over [B][S][D]
  int flat = i * 4;
  int d = flat & (D_ - 1);
  int q = (flat >> 8) & (S_ - 1);
  int b = flat >> 19;
  int bh = b * 8 + (d >> 5);
  float l = pl[(size_t)bh * S_ + q] + pl[((size_t)32 + bh) * S_ + q];
  float inv = 1.f / l;
  float4 a = ((const float4*)po)[i];
  float4 c4 = ((const float4*)(po + (size_t)B_ * S_ * D_))[i];
  ushort4 o;
  o.x = f2bf((a.x + c4.x) * inv);
  o.y = f2bf((a.y + c4.y) * inv);
  o.z = f2bf((a.z + c4.z) * inv);
  o.w = f2bf((a.w + c4.w) * inv);
  ((ushort4*)attnbf)[i] = o;
}

// ---- projection GEMM: out = relu(attn @ W + b) ----
__global__ __launch_bounds__(256) void proj_kernel(
    const ushort* __restrict__ attnbf,
    const ushort* __restrict__ wt,
    const float* __restrict__ bias,
    float* __restrict__ out) {
  const int tid = threadIdx.x;
  const int wid = tid >> 6, lane = tid & 63;
  const int c = lane & 15, g = lane >> 4;
  const int m0 = blockIdx.x * 64 + wid * 16;
  const int n0 = blockIdx.y * 64;

  f32x4 acc[4];
#pragma unroll
  for (int nb = 0; nb < 4; ++nb) acc[nb] = (f32x4){0.f, 0.f, 0.f, 0.f};

  for (int k0 = 0; k0 < D_; k0 += 32) {
    bf16x8 fa = load8(attnbf + (size_t)(m0 + c) * D_ + k0 + 8 * g);
#pragma unroll
    for (int nb = 0; nb < 4; ++nb) {
      bf16x8 fb = load8(wt + (size_t)(n0 + nb * 16 + c) * D_ + k0 + 8 * g);
      acc[nb] = __builtin_amdgcn_mfma_f32_16x16x32_bf16(fa, fb, acc[nb], 0, 0, 0);
    }
  }

#pragma unroll
  for (int nb = 0; nb < 4; ++nb) {
    int n = n0 + nb * 16 + c;
    float bv = bias[n];
#pragma unroll
    for (int r = 0; r < 4; ++r) {
      int mrow = m0 + 4 * g + r;
      float v = acc[nb][r] + bv;
      out[(size_t)mrow * D_ + n] = fmaxf(v, 0.f);
    }
  }
}

extern "C" void kernel_launch(void* const* d_in, const int* in_sizes, int n_in,
                              void* d_out, int out_size, void* d_ws, size_t ws_size,
                              hipStream_t stream) {
  const float* x = (const float*)d_in[0];     // [B,S,D]
  const float* mask = (const float*)d_in[1];  // [B,S,1]
  const float* pos = (const float*)d_in[2];   // [B,S,D]
  const float* W = (const float*)d_in[3];     // [D,D]
  const float* bias = (const float*)d_in[4];  // [D]
  float* out = (float*)d_out;

  const size_t NE = (size_t)B_ * S_ * D_;  // 2097152
  // ws: posbf 4MB | vtbuf 4MB | wtbuf 128KB | maskp 16KB | po 16MB | pl 512KB
  ushort* posbf = (ushort*)d_ws;
  ushort* vtbuf = posbf + NE;
  ushort* wtbuf = vtbuf + NE;                   // D*D = 65536
  ushort* maskpbuf = wtbuf + (size_t)D_ * D_;   // B*S = 8192
  float* po = (float*)(maskpbuf + (size_t)B_ * S_);
  float* pl = po + 2 * NE;                      // 2*32*S = 131072
  ushort* attnbf = posbf;                       // reuse posbf after attn completes

  cvt_bf16_kernel<<<(int)(NE / 4 / 256), 256, 0, stream>>>(pos, posbf, (int)(NE / 4));
  build_vt_kernel<<<dim3(S_ / 32, B_ * H_), dim3(32, 32), 0, stream>>>(x, mask, vtbuf);
  build_maskp_kernel<<<(B_ * S_) / 256, 256, 0, stream>>>(mask, maskpbuf, B_ * S_);
  build_wt_kernel<<<dim3(D_ / 32, D_ / 32), dim3(32, 32), 0, stream>>>(W, wtbuf);
  attn_kernel<<<dim3(1024, 2), 256, 0, stream>>>(posbf, vtbuf, maskpbuf, po, pl);
  combine_kernel<<<(int)(NE / 4 / 256), 256, 0, stream>>>(po, pl, attnbf);
  proj_kernel<<<dim3((B_ * S_) / 64, D_ / 64), 256, 0, stream>>>(attnbf, wtbuf, bias, out);
}

// Round 10
// 67.361 us; speedup vs baseline: 1.1352x; 1.1352x over previous
//
#include <hip/hip_runtime.h>
#include <hip/hip_bf16.h>
#include <math.h>

#define B_ 4
#define S_ 2048
#define D_ 256
#define H_ 8

typedef __attribute__((ext_vector_type(8))) __bf16 bf16x8;
typedef __attribute__((ext_vector_type(4))) float f32x4;

__device__ inline ushort f2bf(float x) {
  unsigned u = __builtin_bit_cast(unsigned, x);
  unsigned r = u + 0x7fffu + ((u >> 16) & 1u);
  return (ushort)(r >> 16);
}

__device__ inline float bf2f(ushort u) {
  unsigned v = ((unsigned)u) << 16;
  return __builtin_bit_cast(float, v);
}

__device__ inline unsigned cvtpk(float lo, float hi) {
  unsigned r;
  asm("v_cvt_pk_bf16_f32 %0, %1, %2" : "=v"(r) : "v"(lo), "v"(hi));
  return r;
}

__device__ inline bf16x8 load8(const ushort* p) {
  return __builtin_bit_cast(bf16x8, *(const uint4*)p);
}

// ---- prepass: f32 -> bf16 (pos) ----
__global__ void cvt_bf16_kernel(const float* __restrict__ in, ushort* __restrict__ out, int n4) {
  int i = blockIdx.x * blockDim.x + threadIdx.x;
  if (i >= n4) return;
  float4 v = ((const float4*)in)[i];
  ushort4 o;
  o.x = f2bf(v.x); o.y = f2bf(v.y); o.z = f2bf(v.z); o.w = f2bf(v.w);
  ((ushort4*)out)[i] = o;
}

// ---- prepass: Vt[bh][d][s], mask folded in, key-permuted columns per 32-tile ----
__global__ void build_vt_kernel(const float* __restrict__ x, const float* __restrict__ mask,
                                ushort* __restrict__ vt) {
  __shared__ ushort tile[32][33];
  int s0 = blockIdx.x * 32;
  int bh = blockIdx.y;
  int b = bh >> 3, h = bh & 7;
  int tx = threadIdx.x, ty = threadIdx.y;
  float mval = mask[b * S_ + s0 + ty];
  tile[ty][tx] = f2bf(x[((size_t)(b * S_ + s0 + ty)) * D_ + h * 32 + tx] * mval);
  __syncthreads();
  int kx = ((tx >> 1) & 12) + (tx & 3) + ((tx & 4) << 2);  // kappa(tx)
  vt[((size_t)bh * 32 + ty) * S_ + s0 + tx] = tile[kx][ty];
}

// ---- prepass: kappa-permuted bf16 mask ----
__global__ void build_maskp_kernel(const float* __restrict__ mask, ushort* __restrict__ maskp, int n) {
  int i = blockIdx.x * blockDim.x + threadIdx.x;
  if (i >= n) return;
  int t = i & 31;
  int kx = ((t >> 1) & 12) + (t & 3) + ((t & 4) << 2);
  maskp[i] = f2bf(mask[(i & ~31) + kx]);
}

// ---- prepass: Wt[n][k] = W[k][n] as bf16 ----
__global__ void build_wt_kernel(const float* __restrict__ w, ushort* __restrict__ wt) {
  __shared__ ushort tile[32][33];
  int k0 = blockIdx.x * 32;
  int n0 = blockIdx.y * 32;
  int tx = threadIdx.x, ty = threadIdx.y;
  tile[ty][tx] = f2bf(w[(k0 + ty) * D_ + n0 + tx]);
  __syncthreads();
  wt[(n0 + ty) * D_ + k0 + tx] = tile[tx][ty];
}

// ---- flash attention: 64 q per wave, in-block split-K x4, 4-buffer LDS combine
//      (R5-green structure; lo stored as bf16 -> LDS ~17.7 KB) ----
__global__ __launch_bounds__(256, 3) void attn_kernel(
    const ushort* __restrict__ posbf,
    const ushort* __restrict__ vt,
    const ushort* __restrict__ maskp,
    ushort* __restrict__ attnbf) {
  __shared__ ushort lo[4][64][32];  // [wave][q][d] bf16 partial outputs
  __shared__ float ll[4][64];       // [wave][q] partial lsums (f32)
  __shared__ float linv[64];

  const int tid = threadIdx.x;
  const int wid = tid >> 6, lane = tid & 63;
  const int c = lane & 15, g = lane >> 4;
  const int blk = blockIdx.x;
  const int bh = blk & 31;   // XCD co-location: all blocks of one bh -> same XCD
  const int qc = blk >> 5;   // 0..31
  const int b = bh >> 3, h = bh & 7;
  const int q0 = qc * 64;
  const int koff = wid * 512;  // this wave's key quarter

  const ushort* posb = posbf + (size_t)b * S_ * D_;
  const ushort* vtb = vt + (size_t)bh * 32 * S_;

  // 4 Q fragments (B' operand): col j covers queries q0+16j+c
  bf16x8 fq[4];
#pragma unroll
  for (int j = 0; j < 4; ++j)
    fq[j] = load8(posb + (size_t)(q0 + 16 * j + c) * D_ + h * 32 + g * 8);

  const ushort* kb = posb + (size_t)(koff + c) * D_ + h * 32 + g * 8;
  const ushort* vb = vtb + (size_t)c * S_ + koff + g * 8;
  const ushort* mb = maskp + (size_t)b * S_ + koff + g * 8;

  const f32x4 zero = {0.f, 0.f, 0.f, 0.f};
  f32x4 o0[4], o1[4], o2[4];
#pragma unroll
  for (int j = 0; j < 4; ++j) { o0[j] = zero; o1[j] = zero; o2[j] = zero; }

  const float C1 = 0.42044820762685725f * 1.44269504088896340f; // RS * log2e
  const float C2 = -16.0f * 1.44269504088896340f;               // -OFF * log2e

  bf16x8 ak0 = load8(kb);
  bf16x8 ak1 = load8(kb + 16 * D_);
  bf16x8 av0 = load8(vb);
  bf16x8 av1 = load8(vb + 16 * S_);
  bf16x8 am  = load8(mb);

  for (int t = 0; t < 16; ++t) {
    int tn = (t + 1) & 15;  // wraps; final reload unused
    const ushort* kbn = kb + (size_t)tn * 32 * D_;
    bf16x8 nk0 = load8(kbn);
    bf16x8 nk1 = load8(kbn + 16 * D_);
    bf16x8 nv0 = load8(vb + tn * 32);
    bf16x8 nv1 = load8(vb + 16 * S_ + tn * 32);
    bf16x8 nm  = load8(mb + tn * 32);

#pragma unroll
    for (int j = 0; j < 4; ++j) {
      f32x4 s0 = __builtin_amdgcn_mfma_f32_16x16x32_bf16(ak0, fq[j], zero, 0, 0, 0);
      f32x4 s1 = __builtin_amdgcn_mfma_f32_16x16x32_bf16(ak1, fq[j], zero, 0, 0, 0);

      float p0 = __builtin_amdgcn_exp2f(fmaf(s0[0], C1, C2));
      float p1 = __builtin_amdgcn_exp2f(fmaf(s0[1], C1, C2));
      float p2 = __builtin_amdgcn_exp2f(fmaf(s0[2], C1, C2));
      float p3 = __builtin_amdgcn_exp2f(fmaf(s0[3], C1, C2));
      float p4 = __builtin_amdgcn_exp2f(fmaf(s1[0], C1, C2));
      float p5 = __builtin_amdgcn_exp2f(fmaf(s1[1], C1, C2));
      float p6 = __builtin_amdgcn_exp2f(fmaf(s1[2], C1, C2));
      float p7 = __builtin_amdgcn_exp2f(fmaf(s1[3], C1, C2));

      uint4 uw = make_uint4(cvtpk(p0, p1), cvtpk(p2, p3), cvtpk(p4, p5), cvtpk(p6, p7));
      bf16x8 fp = __builtin_bit_cast(bf16x8, uw);

      o0[j] = __builtin_amdgcn_mfma_f32_16x16x32_bf16(fp, av0, o0[j], 0, 0, 0);
      o1[j] = __builtin_amdgcn_mfma_f32_16x16x32_bf16(fp, av1, o1[j], 0, 0, 0);
      o2[j] = __builtin_amdgcn_mfma_f32_16x16x32_bf16(fp, am, o2[j], 0, 0, 0);
    }

    ak0 = nk0; ak1 = nk1; av0 = nv0; av1 = nv1; am = nm;
  }

  // deposit wave partials to LDS (bf16)
#pragma unroll
  for (int j = 0; j < 4; ++j) {
#pragma unroll
    for (int r = 0; r < 4; ++r) {
      int ql = 16 * j + 4 * g + r;
      lo[wid][ql][c] = f2bf(o0[j][r]);
      lo[wid][ql][16 + c] = f2bf(o1[j][r]);
      if (c == 0) ll[wid][ql] = o2[j][r];
    }
  }
  __syncthreads();
  if (tid < 64) {
    float l = ll[0][tid] + ll[1][tid] + ll[2][tid] + ll[3][tid];
    linv[tid] = 1.f / l;
  }
  __syncthreads();

  // reduce 4 wave-partials and write bf16 output
  for (int e = tid; e < 64 * 32; e += 256) {
    int q = e >> 5, d = e & 31;
    float s = bf2f(lo[0][q][d]) + bf2f(lo[1][q][d]) + bf2f(lo[2][q][d]) + bf2f(lo[3][q][d]);
    attnbf[(size_t)(b * S_ + q0 + q) * D_ + h * 32 + d] = f2bf(s * linv[q]);
  }
}

// ---- projection GEMM: out = relu(attn @ W + b) ----
__global__ __launch_bounds__(256) void proj_kernel(
    const ushort* __restrict__ attnbf,
    const ushort* __restrict__ wt,
    const float* __restrict__ bias,
    float* __restrict__ out) {
  const int tid = threadIdx.x;
  const int wid = tid >> 6, lane = tid & 63;
  const int c = lane & 15, g = lane >> 4;
  const int m0 = blockIdx.x * 64 + wid * 16;
  const int n0 = blockIdx.y * 64;

  f32x4 acc[4];
#pragma unroll
  for (int nb = 0; nb < 4; ++nb) acc[nb] = (f32x4){0.f, 0.f, 0.f, 0.f};

  for (int k0 = 0; k0 < D_; k0 += 32) {
    bf16x8 fa = load8(attnbf + (size_t)(m0 + c) * D_ + k0 + 8 * g);
#pragma unroll
    for (int nb = 0; nb < 4; ++nb) {
      bf16x8 fb = load8(wt + (size_t)(n0 + nb * 16 + c) * D_ + k0 + 8 * g);
      acc[nb] = __builtin_amdgcn_mfma_f32_16x16x32_bf16(fa, fb, acc[nb], 0, 0, 0);
    }
  }

#pragma unroll
  for (int nb = 0; nb < 4; ++nb) {
    int n = n0 + nb * 16 + c;
    float bv = bias[n];
#pragma unroll
    for (int r = 0; r < 4; ++r) {
      int mrow = m0 + 4 * g + r;
      float v = acc[nb][r] + bv;
      out[(size_t)mrow * D_ + n] = fmaxf(v, 0.f);
    }
  }
}

extern "C" void kernel_launch(void* const* d_in, const int* in_sizes, int n_in,
                              void* d_out, int out_size, void* d_ws, size_t ws_size,
                              hipStream_t stream) {
  const float* x = (const float*)d_in[0];     // [B,S,D]
  const float* mask = (const float*)d_in[1];  // [B,S,1]
  const float* pos = (const float*)d_in[2];   // [B,S,D]
  const float* W = (const float*)d_in[3];     // [D,D]
  const float* bias = (const float*)d_in[4];  // [D]
  float* out = (float*)d_out;

  const size_t NE = (size_t)B_ * S_ * D_;  // 2097152
  ushort* posbf = (ushort*)d_ws;
  ushort* vtbuf = posbf + NE;
  ushort* attnbf = vtbuf + NE;
  ushort* wtbuf = attnbf + NE;                 // D*D = 65536
  ushort* maskpbuf = wtbuf + (size_t)D_ * D_;  // B*S = 8192

  cvt_bf16_kernel<<<(int)(NE / 4 / 256), 256, 0, stream>>>(pos, posbf, (int)(NE / 4));
  build_vt_kernel<<<dim3(S_ / 32, B_ * H_), dim3(32, 32), 0, stream>>>(x, mask, vtbuf);
  build_maskp_kernel<<<(B_ * S_) / 256, 256, 0, stream>>>(mask, maskpbuf, B_ * S_);
  build_wt_kernel<<<dim3(D_ / 32, D_ / 32), dim3(32, 32), 0, stream>>>(W, wtbuf);
  attn_kernel<<<1024, 256, 0, stream>>>(posbf, vtbuf, maskpbuf, attnbf);
  proj_kernel<<<dim3((B_ * S_) / 64, D_ / 64), 256, 0, stream>>>(attnbf, wtbuf, bias, out);
}